// Round 2
// baseline (345.807 us; speedup 1.0000x reference)
//
#include <hip/hip_runtime.h>
#include <math.h>

#define NUM_TOKENS 16384
#define HIDDEN 2048
#define NUM_EXPERTS 64

// out layout (fp32 flat): [0,32768) weights [t][2]; [32768,65536) indices as float; [65536] aux
#define IDX_OFF 32768
#define AUX_OFF 65536

#define KSLICE 256   // k-depth per wave (8 waves cover HIDDEN=2048)

__global__ __launch_bounds__(512) void router_kernel(
    const float* __restrict__ x, const float* __restrict__ Wg,
    float* __restrict__ out, float* __restrict__ ws)
{
    __shared__ float buf[4][64][68];   // partial-logit tree buffers (stride 68 kills conflicts)
    __shared__ int top1s[64];

    const int tid  = threadIdx.x;
    const int w    = tid >> 6;         // wave 0..7 = k-slice
    const int lane = tid & 63;         // lane = token-within-block
    const int token = blockIdx.x * 64 + lane;

    const int k0 = __builtin_amdgcn_readfirstlane(w) * KSLICE;  // scalar -> W addrs uniform

    float C[64];
    #pragma unroll
    for (int e = 0; e < 64; ++e) C[e] = 0.f;

    const float4* xr = reinterpret_cast<const float4*>(x + (size_t)token * HIDDEN + k0);

    float4 xc[4], xn[4];
    #pragma unroll
    for (int j = 0; j < 4; ++j) xc[j] = xr[j];

    for (int c = 0; c < 16; ++c) {
        if (c < 15) {
            #pragma unroll
            for (int j = 0; j < 4; ++j) xn[j] = xr[(c + 1) * 4 + j];   // prefetch next chunk
        }
        const int kbase = k0 + c * 16;
        #pragma unroll
        for (int j = 0; j < 4; ++j) {
            const float xv[4] = {xc[j].x, xc[j].y, xc[j].z, xc[j].w};
            #pragma unroll
            for (int q = 0; q < 4; ++q) {
                const int k = kbase + j * 4 + q;                        // fully scalar
                const float4* wr = reinterpret_cast<const float4*>(Wg + (size_t)k * NUM_EXPERTS);
                #pragma unroll
                for (int e4 = 0; e4 < 16; ++e4) {
                    const float4 wv = wr[e4];
                    C[e4*4+0] = fmaf(xv[q], wv.x, C[e4*4+0]);
                    C[e4*4+1] = fmaf(xv[q], wv.y, C[e4*4+1]);
                    C[e4*4+2] = fmaf(xv[q], wv.z, C[e4*4+2]);
                    C[e4*4+3] = fmaf(xv[q], wv.w, C[e4*4+3]);
                }
            }
        }
        if (c < 15) {
            #pragma unroll
            for (int j = 0; j < 4; ++j) xc[j] = xn[j];
        }
    }

    #define WBUF(b) { _Pragma("unroll") for (int e4 = 0; e4 < 16; ++e4) { \
        float4 v; v.x = C[e4*4+0]; v.y = C[e4*4+1]; v.z = C[e4*4+2]; v.w = C[e4*4+3]; \
        *reinterpret_cast<float4*>(&buf[b][lane][e4*4]) = v; } }
    #define ABUF(b) { _Pragma("unroll") for (int e4 = 0; e4 < 16; ++e4) { \
        const float4 v = *reinterpret_cast<const float4*>(&buf[b][lane][e4*4]); \
        C[e4*4+0] += v.x; C[e4*4+1] += v.y; C[e4*4+2] += v.z; C[e4*4+3] += v.w; } }

    // 3-round tree: 8 partials -> wave 0
    if (w >= 4) WBUF(w - 4);
    __syncthreads();
    if (w < 4) ABUF(w);
    __syncthreads();
    if (w == 2 || w == 3) WBUF(w - 2);
    __syncthreads();
    if (w < 2) ABUF(w);
    __syncthreads();
    if (w == 1) WBUF(0);
    __syncthreads();

    if (w == 0) {
        ABUF(0);   // full logits for this token, lane-local in C[64]

        float m = C[0];
        #pragma unroll
        for (int e = 1; e < 64; ++e) m = fmaxf(m, C[e]);
        float Z = 0.f;
        #pragma unroll
        for (int e = 0; e < 64; ++e) { C[e] = expf(C[e] - m); Z += C[e]; }
        const float rz = 1.f / Z;

        float v1 = -1.f, v2 = -1.f; int i1 = 0, i2 = 0;
        #pragma unroll
        for (int e = 0; e < 64; ++e) {
            const float p = C[e] * rz;
            C[e] = p;
            if (p > v1)      { v2 = v1; i2 = i1; v1 = p; i1 = e; }
            else if (p > v2) { v2 = p;  i2 = e; }
        }

        const float s = v1 + v2 + 1e-9f;
        float2 wo; wo.x = v1 / s; wo.y = v2 / s;
        *reinterpret_cast<float2*>(&out[(size_t)token * 2]) = wo;
        float2 io; io.x = (float)i1; io.y = (float)i2;
        *reinterpret_cast<float2*>(&out[IDX_OFF + (size_t)token * 2]) = io;

        WBUF(0);             // stash probs for aux column-sums
        top1s[lane] = i1;
    }
    __syncthreads();

    if (w == 1) {            // lane = expert
        float sp = 0.f;
        #pragma unroll 8
        for (int t = 0; t < 64; ++t) sp += buf[0][t][lane];
        float cnt = 0.f;
        #pragma unroll 8
        for (int t = 0; t < 64; ++t) cnt += (top1s[t] == lane) ? 1.f : 0.f;
        ws[(size_t)blockIdx.x * 128 + lane]      = sp;
        ws[(size_t)blockIdx.x * 128 + 64 + lane] = cnt;
    }
}

__global__ __launch_bounds__(64) void finalize_kernel(
    const float* __restrict__ ws, float* __restrict__ out)
{
    const int e = threadIdx.x;  // 0..63
    float sp = 0.f, sc = 0.f;
    for (int b = 0; b < NUM_TOKENS / 64; ++b) {
        sp += ws[(size_t)b * 128 + e];
        sc += ws[(size_t)b * 128 + 64 + e];
    }
    float val = (sc * (1.0f / NUM_TOKENS)) * (sp * (1.0f / NUM_TOKENS));
    #pragma unroll
    for (int off = 32; off >= 1; off >>= 1) val += __shfl_xor(val, off);
    if (e == 0) out[AUX_OFF] = (float)NUM_EXPERTS * val;
}

extern "C" void kernel_launch(void* const* d_in, const int* in_sizes, int n_in,
                              void* d_out, int out_size, void* d_ws, size_t ws_size,
                              hipStream_t stream) {
    const float* x  = (const float*)d_in[0];
    const float* Wg = (const float*)d_in[1];
    float* out = (float*)d_out;
    float* ws  = (float*)d_ws;

    router_kernel<<<NUM_TOKENS / 64, 512, 0, stream>>>(x, Wg, out, ws);
    finalize_kernel<<<1, 64, 0, stream>>>(ws, out);
}

// Round 3
// 104.576 us; speedup vs baseline: 3.3068x; 3.3068x over previous
//
#include <hip/hip_runtime.h>
#include <math.h>

#define NUM_TOKENS 16384
#define HIDDEN 2048
#define NUM_EXPERTS 64

// out layout (fp32 flat): [0,32768) weights [t][2]; [32768,65536) indices as float; [65536] aux
#define IDX_OFF 32768
#define AUX_OFF 65536

#define KSLICE 256   // k-depth per wave (8 waves cover HIDDEN=2048)

__global__ __launch_bounds__(512, 2) void router_kernel(
    const float* __restrict__ x, const float* __restrict__ Wg,
    float* __restrict__ out, float* __restrict__ ws)
{
    __shared__ float buf[4][64][68];   // partial-logit tree buffers
    __shared__ int top1s[64];

    const int tid  = threadIdx.x;
    const int w    = tid >> 6;         // wave 0..7 = k-slice
    const int lane = tid & 63;         // lane = token-within-block
    const int token = blockIdx.x * 64 + lane;

    const int k0 = __builtin_amdgcn_readfirstlane(w) * KSLICE;  // scalar

    float C[64];
    #pragma unroll
    for (int e = 0; e < 64; ++e) C[e] = 0.f;

    const float4* xr = reinterpret_cast<const float4*>(x + (size_t)token * HIDDEN + k0);

    float4 cur = xr[0];
    for (int c = 0; c < KSLICE / 4; ++c) {            // 64 iterations
        float4 nxt = xr[(c + 1) & (KSLICE / 4 - 1)];  // wrap keeps it in-bounds
        const float xv[4] = {cur.x, cur.y, cur.z, cur.w};
        #pragma unroll
        for (int q = 0; q < 4; ++q) {
            const int k = k0 + c * 4 + q;             // fully scalar
            const float* __restrict__ wrow = Wg + (size_t)k * NUM_EXPERTS;
            #pragma unroll
            for (int e = 0; e < 64; ++e)
                C[e] = fmaf(xv[q], wrow[e], C[e]);    // v_fmac_f32 vdst, s_w, v_x
        }
        cur = nxt;
    }

    #define WBUF(b) { _Pragma("unroll") for (int e4 = 0; e4 < 16; ++e4) { \
        float4 v; v.x = C[e4*4+0]; v.y = C[e4*4+1]; v.z = C[e4*4+2]; v.w = C[e4*4+3]; \
        *reinterpret_cast<float4*>(&buf[b][lane][e4*4]) = v; } }
    #define ABUF(b) { _Pragma("unroll") for (int e4 = 0; e4 < 16; ++e4) { \
        const float4 v = *reinterpret_cast<const float4*>(&buf[b][lane][e4*4]); \
        C[e4*4+0] += v.x; C[e4*4+1] += v.y; C[e4*4+2] += v.z; C[e4*4+3] += v.w; } }

    // 3-round tree: 8 partials -> wave 0
    if (w >= 4) WBUF(w - 4);
    __syncthreads();
    if (w < 4) ABUF(w);
    __syncthreads();
    if (w == 2 || w == 3) WBUF(w - 2);
    __syncthreads();
    if (w < 2) ABUF(w);
    __syncthreads();
    if (w == 1) WBUF(0);
    __syncthreads();

    if (w == 0) {
        ABUF(0);   // full logits for this token, lane-local in C[64]

        float m = C[0];
        #pragma unroll
        for (int e = 1; e < 64; ++e) m = fmaxf(m, C[e]);
        float Z = 0.f;
        #pragma unroll
        for (int e = 0; e < 64; ++e) { C[e] = expf(C[e] - m); Z += C[e]; }
        const float rz = 1.f / Z;

        float v1 = -1.f, v2 = -1.f; int i1 = 0, i2 = 0;
        #pragma unroll
        for (int e = 0; e < 64; ++e) {
            const float p = C[e] * rz;
            C[e] = p;
            if (p > v1)      { v2 = v1; i2 = i1; v1 = p; i1 = e; }
            else if (p > v2) { v2 = p;  i2 = e; }
        }

        const float s = v1 + v2 + 1e-9f;
        float2 wo; wo.x = v1 / s; wo.y = v2 / s;
        *reinterpret_cast<float2*>(&out[(size_t)token * 2]) = wo;
        float2 io; io.x = (float)i1; io.y = (float)i2;
        *reinterpret_cast<float2*>(&out[IDX_OFF + (size_t)token * 2]) = io;

        WBUF(0);             // stash probs for aux column-sums
        top1s[lane] = i1;
    }
    __syncthreads();

    if (w == 1) {            // lane = expert
        float sp = 0.f;
        #pragma unroll 8
        for (int t = 0; t < 64; ++t) sp += buf[0][t][lane];
        float cnt = 0.f;
        #pragma unroll 8
        for (int t = 0; t < 64; ++t) cnt += (top1s[t] == lane) ? 1.f : 0.f;
        ws[(size_t)blockIdx.x * 128 + lane]      = sp;
        ws[(size_t)blockIdx.x * 128 + 64 + lane] = cnt;
    }
}

__global__ __launch_bounds__(64) void finalize_kernel(
    const float* __restrict__ ws, float* __restrict__ out)
{
    const int e = threadIdx.x;  // 0..63
    float sp = 0.f, sc = 0.f;
    for (int b = 0; b < NUM_TOKENS / 64; ++b) {
        sp += ws[(size_t)b * 128 + e];
        sc += ws[(size_t)b * 128 + 64 + e];
    }
    float val = (sc * (1.0f / NUM_TOKENS)) * (sp * (1.0f / NUM_TOKENS));
    #pragma unroll
    for (int off = 32; off >= 1; off >>= 1) val += __shfl_xor(val, off);
    if (e == 0) out[AUX_OFF] = (float)NUM_EXPERTS * val;
}

extern "C" void kernel_launch(void* const* d_in, const int* in_sizes, int n_in,
                              void* d_out, int out_size, void* d_ws, size_t ws_size,
                              hipStream_t stream) {
    const float* x  = (const float*)d_in[0];
    const float* Wg = (const float*)d_in[1];
    float* out = (float*)d_out;
    float* ws  = (float*)d_ws;

    router_kernel<<<NUM_TOKENS / 64, 512, 0, stream>>>(x, Wg, out, ws);
    finalize_kernel<<<1, 64, 0, stream>>>(ws, out);
}